// Round 4
// baseline (749.740 us; speedup 1.0000x reference)
//
#include <hip/hip_runtime.h>
#include <hip/hip_cooperative_groups.h>
#include <math.h>

namespace cg = cooperative_groups;

#define N_NODES 100000
#define N_EDGES 1000000
#define HDIM 128
#define NGROUPS (N_EDGES / 4)   // 250000 4-edge groups

typedef float vfloat4 __attribute__((ext_vector_type(4)));

struct Params {
    const int*   node_states;
    const int*   edge_states;
    const float* s;
    const int*   src;
    const int*   dst;
    const int*   brev;
    const float* target;
    const int*   tstep;
    const float* node_emb;
    const float* edge_emb;
    const float* cW;
    const float* cb;
    const float* kW;  const float* kb;
    const float* pW;  const float* pb;
    const float* pnW; const float* pnb;
    const float* iW;  const float* ib;
    float* uv;      // ws: 1024 floats
    float* tabs;    // ws: 132 floats (A 4x16 interleaved, B 4x16, C 4)
    float* acc;     // ws: N floats
    unsigned char* es_idx;  // ws: E bytes
    unsigned char* ns_idx;  // ws: N bytes
    float* out;     // d_out: E floats
    float* loss;    // d_out + E
    int nthreads;
};

__device__ __forceinline__ float wave_reduce(float v) {
    #pragma unroll
    for (int off = 32; off > 0; off >>= 1) v += __shfl_down(v, off, 64);
    return v;
}

__global__ __launch_bounds__(256, 4) void fused(Params p) {
    cg::grid_group grid = cg::this_grid();
    __shared__ float smem[512];           // phase A: wdiff[4][128]; phase C: sf tables
    const int tid  = blockIdx.x * 256 + threadIdx.x;
    const int lane = threadIdx.x & 63;
    const int NT   = p.nthreads;
    const int totalWaves = NT >> 6;
    const int gwave = tid >> 6;

    // invtau
    float invtau;
    {
        int step = p.tstep[0];
        float tau;
        if (step == -1) tau = 0.1f;  // TEMP_EVAL
        else {
            float frac = fminf((float)step / 10000.0f, 1.0f);
            tau = 1.0f + (0.1f - 1.0f) * frac;
        }
        invtau = 1.0f / tau;
    }

    // ---------------- Phase A: pack states, zero acc/loss, tab stage 1 -----
    for (int e = tid; e < N_EDGES; e += NT) {
        int4 st = ((const int4*)p.edge_states)[e];
        p.es_idx[e] = (unsigned char)(st.x + 2 * st.y + 4 * st.z + 8 * st.w);
    }
    for (int n = tid; n < N_NODES; n += NT) {
        int4 st = ((const int4*)p.node_states)[n];
        p.ns_idx[n] = (unsigned char)(st.x + 2 * st.y + 4 * st.z + 8 * st.w);
        p.acc[n] = 0.f;
    }
    if (tid == 0) p.loss[0] = 0.f;

    // stage wdiff into LDS (every block; cheap)
    for (int i = threadIdx.x; i < 512; i += 256) {
        const int h = i >> 7, d = i & 127;
        const float* W = (h == 0) ? p.kW : (h == 1) ? p.pW : (h == 2) ? p.pnW : p.iW;
        smem[i] = W[2 * d] - W[2 * d + 1];
    }
    __syncthreads();

    // uv[row]: one wave per row, grid-stride over 1024 rows
    for (int row = gwave; row < 1024; row += totalWaves) {
        const int half = row >> 9;          // 0 = W_top rows, 1 = W_bot rows
        const int r = row & 511;
        const int h = r >> 7, d = r & 127;
        const int cwrow = half * 128 + d;
        float v = p.cW[cwrow * 128 + lane]      * smem[h * 128 + lane]
                + p.cW[cwrow * 128 + 64 + lane] * smem[h * 128 + 64 + lane];
        v = wave_reduce(v);
        if (lane == 0) p.uv[row] = v * invtau;
    }

    __threadfence();
    grid.sync();

    // ---------------- Phase B: tab stage 2 (132 waves) ---------------------
    for (int w = gwave; w < 132; w += totalWaves) {
        float v;
        if (w < 128) {
            const int isB = w >> 6, h = (w >> 4) & 3, i = w & 15;
            const float* emb = isB ? p.node_emb : p.edge_emb;
            const float* uvp = p.uv + isB * 512 + h * 128;
            v = emb[i * 128 + lane] * uvp[lane] + emb[i * 128 + 64 + lane] * uvp[64 + lane];
        } else {
            const int h = w - 128;
            const float* W = (h == 0) ? p.kW : (h == 1) ? p.pW : (h == 2) ? p.pnW : p.iW;
            v = p.cb[lane]      * (W[2 * lane] - W[2 * lane + 1])
              + p.cb[64 + lane] * (W[2 * (64 + lane)] - W[2 * (64 + lane) + 1]);
        }
        v = wave_reduce(v);
        if (lane == 0) {
            if (w < 64) {
                const int h = (w >> 4) & 3, i = w & 15;
                p.tabs[i * 4 + h] = v;                 // invtau folded via uv
            } else if (w < 128) {
                const int h = (w >> 4) & 3, i = w & 15;
                p.tabs[64 + i * 4 + h] = v;
            } else {
                const int h = w - 128;
                const float* b = (h == 0) ? p.kb : (h == 1) ? p.pb : (h == 2) ? p.pnb : p.ib;
                p.tabs[128 + h] = (v + b[0] - b[1]) * invtau;
            }
        }
    }

    __threadfence();
    grid.sync();

    // ---------------- Phase C: per-edge gates + scatter-add ----------------
    float4* sf = (float4*)smem;  // [0..15] A, [16..31] B, [32] C
    if (threadIdx.x < 33) sf[threadIdx.x] = ((const float4*)p.tabs)[threadIdx.x];
    __syncthreads();

    float lsum = 0.f;
    const float4 c4 = ((const float4*)p.tabs)[32];  // also in sf[32]

    for (int t = tid; t < NGROUPS; t += NT) {
        const int e0 = t * 4;
        const int4   rv = ((const int4*)p.brev)[t];
        const int4   sr = ((const int4*)p.src)[t];
        const int4   ds = ((const int4*)p.dst)[t];
        const float4 sv = ((const float4*)p.s)[t];
        const vfloat4 tg = __builtin_nontemporal_load(&((const vfloat4*)p.target)[t]);

        const int rvv[4] = {rv.x, rv.y, rv.z, rv.w};
        const int srv[4] = {sr.x, sr.y, sr.z, sr.w};
        const int dsv[4] = {ds.x, ds.y, ds.z, ds.w};
        const float svv[4] = {sv.x, sv.y, sv.z, sv.w};
        const float tgv[4] = {tg.x, tg.y, tg.z, tg.w};

        int ei[4], ni[4];
        float sd[4], ss[4];
        #pragma unroll
        for (int j = 0; j < 4; ++j) {
            ei[j] = p.es_idx[rvv[j]];
            ni[j] = p.ns_idx[srv[j]];
            sd[j] = p.s[dsv[j]];
            ss[j] = p.s[srv[j]];
        }

        float ov[4];
        #pragma unroll
        for (int j = 0; j < 4; ++j) {
            const float4 a = sf[ei[j]];
            const float4 b = sf[16 + ni[j]];
            const float lk  = a.x + b.x + c4.x;
            const float lp  = a.y + b.y + c4.y;
            const float lpn = a.z + b.z + c4.z;
            const float li  = a.w + b.w + c4.w;
            const float pk  = 1.f / (1.f + __expf(-lk));
            const float pp  = 1.f / (1.f + __expf(-lp));
            const float ppn = 1.f / (1.f + __expf(-lpn));
            const float pi  = 1.f / (1.f + __expf(-li));

            const float s_wo = svv[j] - sd[j];
            const float s_w  = s_wo + ss[j];
            atomicAdd(&p.acc[dsv[j]], pp * s_wo + ppn * s_w);

            ov[j] = pi + svv[j] * pk;
            if (e0 + j >= N_NODES) {   // out final for non-loop edges
                const float d = tgv[j] - ov[j];
                lsum += d * d;
            }
        }
        float4 o4 = make_float4(ov[0], ov[1], ov[2], ov[3]);
        ((float4*)p.out)[t] = o4;
    }

    __threadfence();
    grid.sync();

    // ---------------- Phase D: node finalize + loss ------------------------
    for (int n = tid; n < N_NODES; n += NT) {
        const float v = p.out[n] + p.acc[n];
        p.out[n] = v;
        const float d = p.target[n] - v;
        lsum += d * d;
    }

    lsum = wave_reduce(lsum);
    __shared__ float wsum[4];
    const int wid = threadIdx.x >> 6;
    if (lane == 0) wsum[wid] = lsum;
    __syncthreads();
    if (threadIdx.x == 0) {
        const float tot = wsum[0] + wsum[1] + wsum[2] + wsum[3];
        atomicAdd(p.loss, tot * (1.0f / (float)N_EDGES));
    }
}

extern "C" void kernel_launch(void* const* d_in, const int* in_sizes, int n_in,
                              void* d_out, int out_size, void* d_ws, size_t ws_size,
                              hipStream_t stream) {
    Params P;
    P.node_states = (const int*)d_in[0];
    P.edge_states = (const int*)d_in[1];
    P.s           = (const float*)d_in[2];
    P.src         = (const int*)d_in[3];
    P.dst         = ((const int*)d_in[3]) + N_EDGES;
    P.brev        = (const int*)d_in[4];
    P.target      = (const float*)d_in[5];
    // d_in[6] = processor_step (batch axis-1 size 1 -> index 0)
    P.tstep       = (const int*)d_in[7];
    P.node_emb = (const float*)d_in[8];
    P.edge_emb = (const float*)d_in[9];
    P.cW  = (const float*)d_in[10];
    P.cb  = (const float*)d_in[11];
    P.kW  = (const float*)d_in[12];  P.kb  = (const float*)d_in[13];
    P.pW  = (const float*)d_in[14];  P.pb  = (const float*)d_in[15];
    P.pnW = (const float*)d_in[16];  P.pnb = (const float*)d_in[17];
    P.iW  = (const float*)d_in[18];  P.ib  = (const float*)d_in[19];

    char* ws = (char*)d_ws;
    P.tabs   = (float*)ws;                               // 132 floats (pad 1 KiB)
    P.uv     = (float*)(ws + 1024);                      // 1024 floats (4 KiB)
    P.acc    = (float*)(ws + 1024 + 4096);               // N floats
    P.es_idx = (unsigned char*)(ws + 1024 + 4096 + (size_t)N_NODES * 4);
    P.ns_idx = P.es_idx + N_EDGES;

    P.out  = (float*)d_out;
    P.loss = (float*)d_out + N_EDGES;

    int bpc = 0;
    hipOccupancyMaxActiveBlocksPerMultiprocessor(&bpc, fused, 256, 0);
    int grid = bpc * 256;          // 256 CUs on MI355X
    if (grid > 1024) grid = 1024;
    if (grid < 64)   grid = 64;    // fallback; grid-stride keeps correctness
    P.nthreads = grid * 256;

    void* args[] = { &P };
    hipLaunchCooperativeKernel(fused, dim3(grid), dim3(256), args, 0, stream);
}

// Round 5
// 184.224 us; speedup vs baseline: 4.0697x; 4.0697x over previous
//
#include <hip/hip_runtime.h>
#include <math.h>

#define N_NODES 100000
#define N_EDGES 1000000
#define HDIM 128
#define N_NONLOOP (N_EDGES - N_NODES)          // 900000 edges needing atomics

typedef float  vfloat2 __attribute__((ext_vector_type(2)));
typedef float  vfloat4 __attribute__((ext_vector_type(4)));

__device__ __forceinline__ float get_invtau(const int* __restrict__ training_step) {
    int step = training_step[0];
    float tau;
    if (step == -1) {
        tau = 0.1f;  // TEMP_EVAL
    } else {
        float frac = fminf((float)step / 10000.0f, 1.0f);
        tau = 1.0f + (0.1f - 1.0f) * frac;
    }
    return 1.0f / tau;
}

__device__ __forceinline__ float wave_reduce(float v) {
    #pragma unroll
    for (int off = 32; off > 0; off >>= 1) v += __shfl_down(v, off, 64);
    return v;
}

// ---------------------------------------------------------------------------
// Table stage 1: uv[0..511]    = (row d of W_top)·wdiff_h · invtau
//                uv[512..1023] = (row 128+d of W_bot)·wdiff_h · invtau
// One wave per row, coalesced combine_W reads. 256 blocks x 256 threads.
// ---------------------------------------------------------------------------
__global__ void tab_stage1(const float* __restrict__ cW,
                           const float* __restrict__ kW, const float* __restrict__ pW,
                           const float* __restrict__ pnW, const float* __restrict__ iW,
                           const int* __restrict__ tstep,
                           float* __restrict__ uv)
{
    __shared__ float wd[512];  // wdiff[h][d]
    const float invtau = get_invtau(tstep);
    for (int i = threadIdx.x; i < 512; i += 256) {
        const int h = i >> 7, d = i & 127;
        const float* W = (h == 0) ? kW : (h == 1) ? pW : (h == 2) ? pnW : iW;
        wd[i] = W[2 * d] - W[2 * d + 1];
    }
    __syncthreads();

    const int row  = blockIdx.x * 4 + (threadIdx.x >> 6);  // 0..1023
    const int lane = threadIdx.x & 63;
    const int half = row >> 9;
    const int r    = row & 511;
    const int h    = r >> 7, d = r & 127;
    const int cwrow = half * 128 + d;

    float p = cW[cwrow * 128 + lane]      * wd[h * 128 + lane]
            + cW[cwrow * 128 + 64 + lane] * wd[h * 128 + 64 + lane];
    p = wave_reduce(p);
    if (lane == 0) uv[row] = p * invtau;
}

// ---------------------------------------------------------------------------
// Table stage 2: tabs as float4-per-index:
//   [0..15] A4 by ei, [16..31] B4 by ni, [32] C4. 33 blocks x 256 threads.
// ---------------------------------------------------------------------------
__global__ void tab_stage2(const float* __restrict__ node_emb,
                           const float* __restrict__ edge_emb,
                           const float* __restrict__ cb,
                           const float* __restrict__ kW, const float* __restrict__ kb,
                           const float* __restrict__ pW, const float* __restrict__ pb,
                           const float* __restrict__ pnW, const float* __restrict__ pnb,
                           const float* __restrict__ iW, const float* __restrict__ ib,
                           const int* __restrict__ tstep,
                           const float* __restrict__ uv,
                           float* __restrict__ tabs)
{
    const int w = blockIdx.x * 4 + (threadIdx.x >> 6);  // 0..131
    if (w >= 132) return;
    const int lane = threadIdx.x & 63;
    const float invtau = get_invtau(tstep);

    float p;
    if (w < 128) {
        const int isB = w >> 6, h = (w >> 4) & 3, i = w & 15;
        const float* emb = isB ? node_emb : edge_emb;
        const float* uvp = uv + isB * 512 + h * 128;
        p = emb[i * 128 + lane] * uvp[lane] + emb[i * 128 + 64 + lane] * uvp[64 + lane];
    } else {
        const int h = w - 128;
        const float* W = (h == 0) ? kW : (h == 1) ? pW : (h == 2) ? pnW : iW;
        p = cb[lane]      * (W[2 * lane] - W[2 * lane + 1])
          + cb[64 + lane] * (W[2 * (64 + lane)] - W[2 * (64 + lane) + 1]);
    }
    p = wave_reduce(p);
    if (lane == 0) {
        if (w < 64) {
            const int h = (w >> 4) & 3, i = w & 15;
            tabs[i * 4 + h] = p;
        } else if (w < 128) {
            const int h = (w >> 4) & 3, i = w & 15;
            tabs[64 + i * 4 + h] = p;
        } else {
            const int h = w - 128;
            const float* b = (h == 0) ? kb : (h == 1) ? pb : (h == 2) ? pnb : ib;
            tabs[128 + h] = (p + b[0] - b[1]) * invtau;
        }
    }
}

// ---------------------------------------------------------------------------
// Pack 4-bit state indices, zero acc + loss.
// ---------------------------------------------------------------------------
__global__ void precompute(const int* __restrict__ node_states,
                           const int* __restrict__ edge_states,
                           unsigned char* __restrict__ es_idx,
                           unsigned char* __restrict__ ns_idx,
                           float* __restrict__ acc,
                           float* __restrict__ loss_out)
{
    const int e = blockIdx.x * blockDim.x + threadIdx.x;
    if (e < N_EDGES) {
        int4 st = ((const int4*)edge_states)[e];
        es_idx[e] = (unsigned char)(st.x + 2 * st.y + 4 * st.z + 8 * st.w);
    }
    if (e < N_NODES) {
        int4 st = ((const int4*)node_states)[e];
        ns_idx[e] = (unsigned char)(st.x + 2 * st.y + 4 * st.z + 8 * st.w);
        acc[e] = 0.f;
    }
    if (e == 0) *loss_out = 0.f;
}

// ---------------------------------------------------------------------------
// Non-loop edges only (e in [N_NODES, N_EDGES)). 2 edges/thread.
// Gates + native-fp32 atomic scatter + out store + loss partial.
// ---------------------------------------------------------------------------
__global__ __launch_bounds__(256) void edge_kernel(
    const float* __restrict__ s,
    const int* __restrict__ src,
    const int* __restrict__ dst,
    const int* __restrict__ brev,
    const unsigned char* __restrict__ es_idx,
    const unsigned char* __restrict__ ns_idx,
    const float* __restrict__ tabs,
    const float* __restrict__ target,
    float* __restrict__ acc,
    float* __restrict__ out,
    float* __restrict__ loss_out)
{
    __shared__ float4 sf[33];  // [0..15] A, [16..31] B, [32] C
    if (threadIdx.x < 33) sf[threadIdx.x] = ((const float4*)tabs)[threadIdx.x];
    __syncthreads();

    const int t = blockIdx.x * blockDim.x + threadIdx.x;   // 0 .. 449999
    float lsum = 0.f;

    if (t < N_NONLOOP / 2) {
        const int g = (N_NODES / 2) + t;  // 8B-aligned pair index into edge arrays
        const int2   rv = ((const int2*)brev)[g];
        const int2   sr = ((const int2*)src)[g];
        const int2   ds = ((const int2*)dst)[g];
        const float2 sv = ((const float2*)s)[g];
        const float2 tg = ((const float2*)target)[g];

        const int rvv[2] = {rv.x, rv.y};
        const int srv[2] = {sr.x, sr.y};
        const int dsv[2] = {ds.x, ds.y};
        const float svv[2] = {sv.x, sv.y};
        const float tgv[2] = {tg.x, tg.y};

        int ei[2], ni[2];
        float sd[2], ss[2];
        #pragma unroll
        for (int j = 0; j < 2; ++j) {
            ei[j] = es_idx[rvv[j]];
            ni[j] = ns_idx[srv[j]];
            sd[j] = s[dsv[j]];
            ss[j] = s[srv[j]];
        }

        const float4 c4 = sf[32];
        float ov[2];
        #pragma unroll
        for (int j = 0; j < 2; ++j) {
            const float4 a = sf[ei[j]];
            const float4 b = sf[16 + ni[j]];
            const float lk  = a.x + b.x + c4.x;
            const float lp  = a.y + b.y + c4.y;
            const float lpn = a.z + b.z + c4.z;
            const float li  = a.w + b.w + c4.w;
            const float pk  = 1.f / (1.f + __expf(-lk));
            const float pp  = 1.f / (1.f + __expf(-lp));
            const float ppn = 1.f / (1.f + __expf(-lpn));
            const float pi  = 1.f / (1.f + __expf(-li));

            const float s_wo = svv[j] - sd[j];
            const float s_w  = s_wo + ss[j];
            unsafeAtomicAdd(&acc[dsv[j]], pp * s_wo + ppn * s_w);  // native global_atomic_add_f32

            ov[j] = pi + svv[j] * pk;
            const float d = tgv[j] - ov[j];
            lsum += d * d;
        }
        vfloat2 o2 = {ov[0], ov[1]};
        __builtin_nontemporal_store(o2, &((vfloat2*)out)[g]);
    }

    lsum = wave_reduce(lsum);
    __shared__ float wsum[4];
    const int lane = threadIdx.x & 63, wid = threadIdx.x >> 6;
    if (lane == 0) wsum[wid] = lsum;
    __syncthreads();
    if (threadIdx.x == 0) {
        const float tot = wsum[0] + wsum[1] + wsum[2] + wsum[3];
        atomicAdd(loss_out, tot * (1.0f / (float)N_EDGES));
    }
}

// ---------------------------------------------------------------------------
// Loop edges (e < N_NODES): src=dst=e so s_wo=0; push contribution is
// ppn*s[e] added locally (no atomic). out[e] = pi + s[e]*pk + ppn*s[e] + acc[e].
// ---------------------------------------------------------------------------
__global__ __launch_bounds__(256) void finalize_nodes(
    const float* __restrict__ s,
    const int* __restrict__ brev,
    const unsigned char* __restrict__ es_idx,
    const unsigned char* __restrict__ ns_idx,
    const float* __restrict__ tabs,
    const float* __restrict__ target,
    const float* __restrict__ acc,
    float* __restrict__ out,
    float* __restrict__ loss_out)
{
    __shared__ float4 sf[33];
    if (threadIdx.x < 33) sf[threadIdx.x] = ((const float4*)tabs)[threadIdx.x];
    __syncthreads();

    const int n = blockIdx.x * blockDim.x + threadIdx.x;
    float sq = 0.f;
    if (n < N_NODES) {
        const int   rev = brev[n];
        const int   ei  = es_idx[rev];
        const int   ni  = ns_idx[n];
        const float sv  = s[n];

        const float4 a = sf[ei];
        const float4 b = sf[16 + ni];
        const float4 c4 = sf[32];
        const float lk  = a.x + b.x + c4.x;
        const float lpn = a.z + b.z + c4.z;
        const float li  = a.w + b.w + c4.w;
        const float pk  = 1.f / (1.f + __expf(-lk));
        const float ppn = 1.f / (1.f + __expf(-lpn));
        const float pi  = 1.f / (1.f + __expf(-li));

        const float v = pi + sv * pk + ppn * sv + acc[n];
        out[n] = v;
        const float d = target[n] - v;
        sq = d * d;
    }
    sq = wave_reduce(sq);
    __shared__ float wsum[4];
    const int lane = threadIdx.x & 63, wid = threadIdx.x >> 6;
    if (lane == 0) wsum[wid] = sq;
    __syncthreads();
    if (threadIdx.x == 0) {
        const float tot = wsum[0] + wsum[1] + wsum[2] + wsum[3];
        atomicAdd(loss_out, tot * (1.0f / (float)N_EDGES));
    }
}

extern "C" void kernel_launch(void* const* d_in, const int* in_sizes, int n_in,
                              void* d_out, int out_size, void* d_ws, size_t ws_size,
                              hipStream_t stream) {
    const int*   node_states   = (const int*)d_in[0];
    const int*   edge_states   = (const int*)d_in[1];
    const float* scalars       = (const float*)d_in[2];
    const int*   edge_index    = (const int*)d_in[3];
    const int*   brev          = (const int*)d_in[4];
    const float* batch_scalars = (const float*)d_in[5];
    // d_in[6] = processor_step (batch axis-1 size 1 -> index 0)
    const int*   training_step = (const int*)d_in[7];
    const float* node_emb  = (const float*)d_in[8];
    const float* edge_emb  = (const float*)d_in[9];
    const float* combine_W = (const float*)d_in[10];
    const float* combine_b = (const float*)d_in[11];
    const float* keep_W  = (const float*)d_in[12];
    const float* keep_b  = (const float*)d_in[13];
    const float* push_W  = (const float*)d_in[14];
    const float* push_b  = (const float*)d_in[15];
    const float* pushn_W = (const float*)d_in[16];
    const float* pushn_b = (const float*)d_in[17];
    const float* inc_W   = (const float*)d_in[18];
    const float* inc_b   = (const float*)d_in[19];

    float* out = (float*)d_out;  // [0..E) new_scalars, [E] loss

    char* ws = (char*)d_ws;
    float* tabs = (float*)ws;                               // 132 floats (pad 1 KiB)
    float* uv   = (float*)(ws + 1024);                      // 1024 floats (4 KiB)
    float* acc  = (float*)(ws + 1024 + 4096);               // N floats
    unsigned char* es_idx = (unsigned char*)(ws + 1024 + 4096 + (size_t)N_NODES * 4);
    unsigned char* ns_idx = es_idx + N_EDGES;

    const int* srcp = edge_index;
    const int* dstp = edge_index + N_EDGES;

    tab_stage1<<<256, 256, 0, stream>>>(combine_W, keep_W, push_W, pushn_W, inc_W,
                                        training_step, uv);
    tab_stage2<<<33, 256, 0, stream>>>(node_emb, edge_emb, combine_b,
                                       keep_W, keep_b, push_W, push_b,
                                       pushn_W, pushn_b, inc_W, inc_b,
                                       training_step, uv, tabs);

    precompute<<<(N_EDGES + 255) / 256, 256, 0, stream>>>(node_states, edge_states,
                                                          es_idx, ns_idx, acc,
                                                          out + N_EDGES);

    const int ethreads = N_NONLOOP / 2;   // 450000
    edge_kernel<<<(ethreads + 255) / 256, 256, 0, stream>>>(
        scalars, srcp, dstp, brev, es_idx, ns_idx, tabs, batch_scalars,
        acc, out, out + N_EDGES);

    finalize_nodes<<<(N_NODES + 255) / 256, 256, 0, stream>>>(
        scalars, brev, es_idx, ns_idx, tabs, batch_scalars, acc, out, out + N_EDGES);
}

// Round 6
// 179.260 us; speedup vs baseline: 4.1824x; 1.0277x over previous
//
#include <hip/hip_runtime.h>
#include <math.h>

#define N_NODES 100000
#define N_EDGES 1000000
#define HDIM 128
#define N_NONLOOP (N_EDGES - N_NODES)          // 900000 edges needing atomics

typedef float  vfloat2 __attribute__((ext_vector_type(2)));
typedef float  vfloat4 __attribute__((ext_vector_type(4)));

__device__ __forceinline__ float get_invtau(const int* __restrict__ training_step) {
    int step = training_step[0];
    float tau;
    if (step == -1) {
        tau = 0.1f;  // TEMP_EVAL
    } else {
        float frac = fminf((float)step / 10000.0f, 1.0f);
        tau = 1.0f + (0.1f - 1.0f) * frac;
    }
    return 1.0f / tau;
}

__device__ __forceinline__ float wave_reduce(float v) {
    #pragma unroll
    for (int off = 32; off > 0; off >>= 1) v += __shfl_down(v, off, 64);
    return v;
}

// ---------------------------------------------------------------------------
// Table stage 1: uv[0..511]    = (row d of W_top)·wdiff_h · invtau
//                uv[512..1023] = (row 128+d of W_bot)·wdiff_h · invtau
// ---------------------------------------------------------------------------
__global__ void tab_stage1(const float* __restrict__ cW,
                           const float* __restrict__ kW, const float* __restrict__ pW,
                           const float* __restrict__ pnW, const float* __restrict__ iW,
                           const int* __restrict__ tstep,
                           float* __restrict__ uv)
{
    __shared__ float wd[512];  // wdiff[h][d]
    const float invtau = get_invtau(tstep);
    for (int i = threadIdx.x; i < 512; i += 256) {
        const int h = i >> 7, d = i & 127;
        const float* W = (h == 0) ? kW : (h == 1) ? pW : (h == 2) ? pnW : iW;
        wd[i] = W[2 * d] - W[2 * d + 1];
    }
    __syncthreads();

    const int row  = blockIdx.x * 4 + (threadIdx.x >> 6);  // 0..1023
    const int lane = threadIdx.x & 63;
    const int half = row >> 9;
    const int r    = row & 511;
    const int h    = r >> 7, d = r & 127;
    const int cwrow = half * 128 + d;

    float p = cW[cwrow * 128 + lane]      * wd[h * 128 + lane]
            + cW[cwrow * 128 + 64 + lane] * wd[h * 128 + 64 + lane];
    p = wave_reduce(p);
    if (lane == 0) uv[row] = p * invtau;
}

// ---------------------------------------------------------------------------
// Table stage 2: tabs as float4-per-index:
//   [0..15] A4 by ei, [16..31] B4 by ni, [32] C4.
// ---------------------------------------------------------------------------
__global__ void tab_stage2(const float* __restrict__ node_emb,
                           const float* __restrict__ edge_emb,
                           const float* __restrict__ cb,
                           const float* __restrict__ kW, const float* __restrict__ kb,
                           const float* __restrict__ pW, const float* __restrict__ pb,
                           const float* __restrict__ pnW, const float* __restrict__ pnb,
                           const float* __restrict__ iW, const float* __restrict__ ib,
                           const int* __restrict__ tstep,
                           const float* __restrict__ uv,
                           float* __restrict__ tabs)
{
    const int w = blockIdx.x * 4 + (threadIdx.x >> 6);  // 0..131
    if (w >= 132) return;
    const int lane = threadIdx.x & 63;
    const float invtau = get_invtau(tstep);

    float p;
    if (w < 128) {
        const int isB = w >> 6, h = (w >> 4) & 3, i = w & 15;
        const float* emb = isB ? node_emb : edge_emb;
        const float* uvp = uv + isB * 512 + h * 128;
        p = emb[i * 128 + lane] * uvp[lane] + emb[i * 128 + 64 + lane] * uvp[64 + lane];
    } else {
        const int h = w - 128;
        const float* W = (h == 0) ? kW : (h == 1) ? pW : (h == 2) ? pnW : iW;
        p = cb[lane]      * (W[2 * lane] - W[2 * lane + 1])
          + cb[64 + lane] * (W[2 * (64 + lane)] - W[2 * (64 + lane) + 1]);
    }
    p = wave_reduce(p);
    if (lane == 0) {
        if (w < 64) {
            const int h = (w >> 4) & 3, i = w & 15;
            tabs[i * 4 + h] = p;
        } else if (w < 128) {
            const int h = (w >> 4) & 3, i = w & 15;
            tabs[64 + i * 4 + h] = p;
        } else {
            const int h = w - 128;
            const float* b = (h == 0) ? kb : (h == 1) ? pb : (h == 2) ? pnb : ib;
            tabs[128 + h] = (p + b[0] - b[1]) * invtau;
        }
    }
}

// ---------------------------------------------------------------------------
// Pack 4-bit edge-state indices; build node_pack[n] = {s[n], ns_idx[n]};
// zero acc + loss.
// ---------------------------------------------------------------------------
__global__ void precompute(const int* __restrict__ node_states,
                           const int* __restrict__ edge_states,
                           const float* __restrict__ s,
                           unsigned char* __restrict__ es_idx,
                           float2* __restrict__ node_pack,
                           float* __restrict__ acc,
                           float* __restrict__ loss_out)
{
    const int e = blockIdx.x * blockDim.x + threadIdx.x;
    if (e < N_EDGES) {
        int4 st = ((const int4*)edge_states)[e];
        es_idx[e] = (unsigned char)(st.x + 2 * st.y + 4 * st.z + 8 * st.w);
    }
    if (e < N_NODES) {
        int4 st = ((const int4*)node_states)[e];
        const int idx = st.x + 2 * st.y + 4 * st.z + 8 * st.w;
        float2 np;
        np.x = s[e];
        np.y = __int_as_float(idx);
        node_pack[e] = np;
        acc[e] = 0.f;
    }
    if (e == 0) *loss_out = 0.f;
}

// ---------------------------------------------------------------------------
// Non-loop edges only (e in [N_NODES, N_EDGES)). 4 edges/thread.
// 3 gathers/edge: es_idx[rev] (1B), node_pack[src] (8B), node_pack[dst].x (4B).
// ---------------------------------------------------------------------------
__global__ __launch_bounds__(256) void edge_kernel(
    const float* __restrict__ s,
    const int* __restrict__ src,
    const int* __restrict__ dst,
    const int* __restrict__ brev,
    const unsigned char* __restrict__ es_idx,
    const float2* __restrict__ node_pack,
    const float* __restrict__ tabs,
    const float* __restrict__ target,
    float* __restrict__ acc,
    float* __restrict__ out,
    float* __restrict__ loss_out)
{
    __shared__ float4 sf[33];  // [0..15] A, [16..31] B, [32] C
    if (threadIdx.x < 33) sf[threadIdx.x] = ((const float4*)tabs)[threadIdx.x];
    __syncthreads();

    const int t = blockIdx.x * blockDim.x + threadIdx.x;   // 0 .. 224999
    float lsum = 0.f;

    if (t < N_NONLOOP / 4) {
        const int g = (N_NODES / 4) + t;  // 16B-aligned quad index into edge arrays
        const int4   rv = ((const int4*)brev)[g];
        const int4   sr = ((const int4*)src)[g];
        const int4   ds = ((const int4*)dst)[g];
        const float4 sv = ((const float4*)s)[g];
        const vfloat4 tg = __builtin_nontemporal_load(&((const vfloat4*)target)[g]);

        const int rvv[4] = {rv.x, rv.y, rv.z, rv.w};
        const int srv[4] = {sr.x, sr.y, sr.z, sr.w};
        const int dsv[4] = {ds.x, ds.y, ds.z, ds.w};
        const float svv[4] = {sv.x, sv.y, sv.z, sv.w};
        const float tgv[4] = {tg.x, tg.y, tg.z, tg.w};

        // issue all gathers up front for maximum memory-level parallelism
        int ei[4];
        float2 np[4];
        float sd[4];
        #pragma unroll
        for (int j = 0; j < 4; ++j) {
            ei[j] = es_idx[rvv[j]];
            np[j] = node_pack[srv[j]];
            sd[j] = node_pack[dsv[j]].x;
        }

        const float4 c4 = sf[32];
        float ov[4];
        #pragma unroll
        for (int j = 0; j < 4; ++j) {
            const int   ni = __float_as_int(np[j].y);
            const float ss = np[j].x;
            const float4 a = sf[ei[j]];
            const float4 b = sf[16 + ni];
            const float lk  = a.x + b.x + c4.x;
            const float lp  = a.y + b.y + c4.y;
            const float lpn = a.z + b.z + c4.z;
            const float li  = a.w + b.w + c4.w;
            const float pk  = 1.f / (1.f + __expf(-lk));
            const float pp  = 1.f / (1.f + __expf(-lp));
            const float ppn = 1.f / (1.f + __expf(-lpn));
            const float pi  = 1.f / (1.f + __expf(-li));

            const float s_wo = svv[j] - sd[j];
            const float s_w  = s_wo + ss;
            unsafeAtomicAdd(&acc[dsv[j]], pp * s_wo + ppn * s_w);

            ov[j] = pi + svv[j] * pk;
            const float d = tgv[j] - ov[j];
            lsum += d * d;
        }
        vfloat4 o4 = {ov[0], ov[1], ov[2], ov[3]};
        __builtin_nontemporal_store(o4, &((vfloat4*)out)[g]);
    }

    lsum = wave_reduce(lsum);
    __shared__ float wsum[4];
    const int lane = threadIdx.x & 63, wid = threadIdx.x >> 6;
    if (lane == 0) wsum[wid] = lsum;
    __syncthreads();
    if (threadIdx.x == 0) {
        const float tot = wsum[0] + wsum[1] + wsum[2] + wsum[3];
        atomicAdd(loss_out, tot * (1.0f / (float)N_EDGES));
    }
}

// ---------------------------------------------------------------------------
// Loop edges (e < N_NODES): src=dst=e so s_wo=0; push contribution ppn*s[e]
// is local (no atomic). out[e] = pi + s[e]*(pk + ppn) + acc[e].
// ---------------------------------------------------------------------------
__global__ __launch_bounds__(256) void finalize_nodes(
    const int* __restrict__ brev,
    const unsigned char* __restrict__ es_idx,
    const float2* __restrict__ node_pack,
    const float* __restrict__ tabs,
    const float* __restrict__ target,
    const float* __restrict__ acc,
    float* __restrict__ out,
    float* __restrict__ loss_out)
{
    __shared__ float4 sf[33];
    if (threadIdx.x < 33) sf[threadIdx.x] = ((const float4*)tabs)[threadIdx.x];
    __syncthreads();

    const int n = blockIdx.x * blockDim.x + threadIdx.x;
    float sq = 0.f;
    if (n < N_NODES) {
        const int    rev = brev[n];
        const int    ei  = es_idx[rev];
        const float2 np  = node_pack[n];
        const int    ni  = __float_as_int(np.y);
        const float  sv  = np.x;

        const float4 a = sf[ei];
        const float4 b = sf[16 + ni];
        const float4 c4 = sf[32];
        const float lk  = a.x + b.x + c4.x;
        const float lpn = a.z + b.z + c4.z;
        const float li  = a.w + b.w + c4.w;
        const float pk  = 1.f / (1.f + __expf(-lk));
        const float ppn = 1.f / (1.f + __expf(-lpn));
        const float pi  = 1.f / (1.f + __expf(-li));

        const float v = pi + sv * (pk + ppn) + acc[n];
        out[n] = v;
        const float d = target[n] - v;
        sq = d * d;
    }
    sq = wave_reduce(sq);
    __shared__ float wsum[4];
    const int lane = threadIdx.x & 63, wid = threadIdx.x >> 6;
    if (lane == 0) wsum[wid] = sq;
    __syncthreads();
    if (threadIdx.x == 0) {
        const float tot = wsum[0] + wsum[1] + wsum[2] + wsum[3];
        atomicAdd(loss_out, tot * (1.0f / (float)N_EDGES));
    }
}

extern "C" void kernel_launch(void* const* d_in, const int* in_sizes, int n_in,
                              void* d_out, int out_size, void* d_ws, size_t ws_size,
                              hipStream_t stream) {
    const int*   node_states   = (const int*)d_in[0];
    const int*   edge_states   = (const int*)d_in[1];
    const float* scalars       = (const float*)d_in[2];
    const int*   edge_index    = (const int*)d_in[3];
    const int*   brev          = (const int*)d_in[4];
    const float* batch_scalars = (const float*)d_in[5];
    // d_in[6] = processor_step (batch axis-1 size 1 -> index 0)
    const int*   training_step = (const int*)d_in[7];
    const float* node_emb  = (const float*)d_in[8];
    const float* edge_emb  = (const float*)d_in[9];
    const float* combine_W = (const float*)d_in[10];
    const float* combine_b = (const float*)d_in[11];
    const float* keep_W  = (const float*)d_in[12];
    const float* keep_b  = (const float*)d_in[13];
    const float* push_W  = (const float*)d_in[14];
    const float* push_b  = (const float*)d_in[15];
    const float* pushn_W = (const float*)d_in[16];
    const float* pushn_b = (const float*)d_in[17];
    const float* inc_W   = (const float*)d_in[18];
    const float* inc_b   = (const float*)d_in[19];

    float* out = (float*)d_out;  // [0..E) new_scalars, [E] loss

    char* ws = (char*)d_ws;
    float*  tabs = (float*)ws;                                   // 132 floats (pad 1 KiB)
    float*  uv   = (float*)(ws + 1024);                          // 1024 floats (4 KiB)
    float*  acc  = (float*)(ws + 1024 + 4096);                   // N floats (400 KB)
    float2* node_pack = (float2*)(ws + 1024 + 4096 + (size_t)N_NODES * 4);  // N float2 (800 KB)
    unsigned char* es_idx = (unsigned char*)(ws + 1024 + 4096 + (size_t)N_NODES * 12); // E bytes

    const int* srcp = edge_index;
    const int* dstp = edge_index + N_EDGES;

    tab_stage1<<<256, 256, 0, stream>>>(combine_W, keep_W, push_W, pushn_W, inc_W,
                                        training_step, uv);
    tab_stage2<<<33, 256, 0, stream>>>(node_emb, edge_emb, combine_b,
                                       keep_W, keep_b, push_W, push_b,
                                       pushn_W, pushn_b, inc_W, inc_b,
                                       training_step, uv, tabs);

    precompute<<<(N_EDGES + 255) / 256, 256, 0, stream>>>(node_states, edge_states,
                                                          scalars, es_idx, node_pack,
                                                          acc, out + N_EDGES);

    const int ethreads = N_NONLOOP / 4;   // 225000
    edge_kernel<<<(ethreads + 255) / 256, 256, 0, stream>>>(
        scalars, srcp, dstp, brev, es_idx, node_pack, tabs, batch_scalars,
        acc, out, out + N_EDGES);

    finalize_nodes<<<(N_NODES + 255) / 256, 256, 0, stream>>>(
        brev, es_idx, node_pack, tabs, batch_scalars, acc, out, out + N_EDGES);
}